// Round 10
// baseline (141.667 us; speedup 1.0000x reference)
//
#include <hip/hip_runtime.h>

typedef unsigned short u16;
typedef unsigned int u32;
typedef __bf16 bf16x8 __attribute__((ext_vector_type(8)));
typedef float f32x4 __attribute__((ext_vector_type(4)));

#define MFMA16(a, b, c) __builtin_amdgcn_mfma_f32_16x16x32_bf16(a, b, c, 0, 0, 0)
#define EXP2(x) __builtin_amdgcn_exp2f(x)

typedef const void __attribute__((address_space(1)))* gas1_t;
typedef void __attribute__((address_space(3)))* las3_t;

__device__ __forceinline__ void gload16(const void* g, void* l) {
  __builtin_amdgcn_global_load_lds((gas1_t)g, (las3_t)l, 16, 0, 0);
}

__device__ __forceinline__ u16 f2bf(float f) {
  union { float f; u32 u; } v; v.f = f;
  u32 r = v.u + 0x7FFFu + ((v.u >> 16) & 1u);
  return (u16)(r >> 16);
}

// fast tanh via native exp2: tanh(x) = (e^2x - 1)/(e^2x + 1); bf16-accurate
__device__ __forceinline__ float fast_tanh(float x) {
  float xc = fminf(fmaxf(x, -20.f), 20.f);
  float t = EXP2(xc * 2.885390081777927f);  // 2*log2(e)
  return (t - 1.0f) * __builtin_amdgcn_rcpf(t + 1.0f);
}

// ---------------- elementwise f32 -> bf16 convert (8 elems/thread) ----------
__global__ __launch_bounds__(256) void cvt_kernel(const float* __restrict__ in,
                                                  u16* __restrict__ out, int n8) {
  int i = blockIdx.x * blockDim.x + threadIdx.x;
  int stride = gridDim.x * blockDim.x;
  for (; i < n8; i += stride) {
    const float4* p = (const float4*)(in + (size_t)i * 8);
    float4 a = p[0], b = p[1];
    u16 t[8];
    t[0] = f2bf(a.x); t[1] = f2bf(a.y); t[2] = f2bf(a.z); t[3] = f2bf(a.w);
    t[4] = f2bf(b.x); t[5] = f2bf(b.y); t[6] = f2bf(b.z); t[7] = f2bf(b.w);
    *(uint4*)(out + (size_t)i * 8) = *(uint4*)t;
  }
}

// ------------- w [H][E=1024][D=128] f32 -> wT [H][D][E] bf16 ----------------
__global__ __launch_bounds__(256) void wtrans_kernel(const float* __restrict__ w,
                                                     u16* __restrict__ wT) {
  __shared__ float t[64][65];
  int h = blockIdx.z;
  int e0 = blockIdx.x * 64, d0 = blockIdx.y * 64;
  const float* src = w + (size_t)h * 1024 * 128;
  u16* dst = wT + (size_t)h * 128 * 1024;
  int tid = threadIdx.x;
  {
    int row = tid >> 2, c0 = (tid & 3) * 16;
#pragma unroll
    for (int i = 0; i < 4; ++i) {
      float4 v = *(const float4*)(src + (size_t)(e0 + row) * 128 + d0 + c0 + i * 4);
      t[row][c0 + i * 4 + 0] = v.x;
      t[row][c0 + i * 4 + 1] = v.y;
      t[row][c0 + i * 4 + 2] = v.z;
      t[row][c0 + i * 4 + 3] = v.w;
    }
  }
  __syncthreads();
  {
    int dl = tid >> 2, c0 = (tid & 3) * 16;
    u16 tmp[16];
#pragma unroll
    for (int i = 0; i < 16; ++i) tmp[i] = f2bf(t[c0 + i][dl]);
    u16* o = dst + (size_t)(d0 + dl) * 1024 + e0 + c0;
    *(uint4*)o = *(uint4*)tmp;
    *(uint4*)(o + 8) = *(uint4*)(tmp + 8);
  }
}

// ======== 8-phase GEMM core (round-9, unchanged), BN=256 ====================
template <int BM>
__device__ __forceinline__ void gemm8_core(const u16* __restrict__ Ab,
                                           const u16* __restrict__ Bb,
                                           int K, u16* lds,
                                           f32x4 (&acc)[BM / 32][4]) {
  constexpr int MH = BM / 64;
  constexpr int HR = BM / 4;
  constexpr int AH = (BM / 2) * 64;
  constexpr int BH = 128 * 64;
  constexpr int BUF = 2 * AH + 2 * BH;
  constexpr int LA = BM / 128;
  const int tid = threadIdx.x, lane = tid & 63, wid = tid >> 6;
  const int wr = wid >> 2, wc = wid & 3, l15 = lane & 15, g = lane >> 4;
  const int nkt = K >> 6;
  const int arow = wr * HR;
  const int brow = wc * 32;

  auto stageA = [&](u16* dstHalf, int mh, int kt) {
#pragma unroll
    for (int i = 0; i < LA; ++i) {
      int c = (wid * LA + i) * 64 + lane;
      int rr = c >> 3, src = (c & 7) ^ (rr & 7);
      int grow = (rr / HR) * (2 * HR) + mh * HR + (rr % HR);
      gload16((const char*)Ab + ((size_t)grow * K + kt * 64 + src * 8) * 2,
              (char*)dstHalf + (wid * LA + i) * 1024);
    }
  };
  auto stageB = [&](u16* dstHalf, int nh, int kt) {
#pragma unroll
    for (int i = 0; i < 2; ++i) {
      int c = (wid * 2 + i) * 64 + lane;
      int cc = c >> 3, src = (c & 7) ^ (cc & 7);
      int gcol = (cc >> 5) * 64 + nh * 32 + (cc & 31);
      gload16((const char*)Bb + ((size_t)gcol * K + kt * 64 + src * 8) * 2,
              (char*)dstHalf + (wid * 2 + i) * 1024);
    }
  };

#define LDAF(half)                                                              \
  _Pragma("unroll") for (int m = 0; m < MH; ++m)                                \
  _Pragma("unroll") for (int kc = 0; kc < 2; ++kc) {                            \
    int r_ = arow + m * 16 + l15;                                               \
    af[m][kc] = *(const bf16x8*)((half) + r_ * 64 + (((kc * 4 + g) ^ (r_ & 7)) << 3)); \
  }
#define LDBF(half)                                                              \
  _Pragma("unroll") for (int n = 0; n < 2; ++n)                                 \
  _Pragma("unroll") for (int kc = 0; kc < 2; ++kc) {                            \
    int r_ = brow + n * 16 + l15;                                               \
    bb[n][kc] = *(const bf16x8*)((half) + r_ * 64 + (((kc * 4 + g) ^ (r_ & 7)) << 3)); \
  }
#define MFMAQ(MB, NB)                                                           \
  __builtin_amdgcn_s_setprio(1);                                                \
  _Pragma("unroll") for (int m = 0; m < MH; ++m)                                \
  _Pragma("unroll") for (int n = 0; n < 2; ++n)                                 \
  _Pragma("unroll") for (int kc = 0; kc < 2; ++kc)                              \
    acc[(MB) * MH + m][(NB) * 2 + n] =                                          \
        MFMA16(af[m][kc], bb[n][kc], acc[(MB) * MH + m][(NB) * 2 + n]);         \
  __builtin_amdgcn_s_setprio(0);

  stageA(lds, 0, 0);
  stageB(lds + 2 * AH, 0, 0);
  stageA(lds + AH, 1, 0);
  stageB(lds + 2 * AH + BH, 1, 0);
  if constexpr (BM == 256) asm volatile("s_waitcnt vmcnt(4)" ::: "memory");
  else                     asm volatile("s_waitcnt vmcnt(3)" ::: "memory");
  __builtin_amdgcn_s_barrier();

  bf16x8 af[MH][2], bb[2][2];
  for (int t = 0; t < nkt; ++t) {
    const int cur = t & 1;
    u16* A0c = lds + cur * BUF;
    u16* A1c = A0c + AH;
    u16* B0c = A0c + 2 * AH;
    u16* B1c = B0c + BH;
    u16* A0n = lds + (cur ^ 1) * BUF;
    u16* A1n = A0n + AH;
    u16* B0n = A0n + 2 * AH;
    u16* B1n = B0n + BH;
    const bool pf = (t + 1 < nkt);
    const int k1 = t + 1;

    asm volatile("s_waitcnt vmcnt(2)" ::: "memory");
    LDAF(A0c);
    LDBF(B0c);
    if (pf) stageA(A0n, 0, k1);
    __builtin_amdgcn_s_barrier();
    MFMAQ(0, 0);
    __builtin_amdgcn_s_barrier();

    if (pf) {
      if constexpr (BM == 256) asm volatile("s_waitcnt vmcnt(2)" ::: "memory");
      else                     asm volatile("s_waitcnt vmcnt(1)" ::: "memory");
    } else {
      asm volatile("s_waitcnt vmcnt(0)" ::: "memory");
    }
    LDAF(A1c);
    if (pf) stageB(B0n, 0, k1);
    __builtin_amdgcn_s_barrier();
    MFMAQ(1, 0);
    __builtin_amdgcn_s_barrier();

    LDBF(B1c);
    if (pf) stageA(A1n, 1, k1);
    __builtin_amdgcn_s_barrier();
    MFMAQ(1, 1);
    __builtin_amdgcn_s_barrier();

    if (pf) {
      if constexpr (BM == 256) asm volatile("s_waitcnt vmcnt(2)" ::: "memory");
      else                     asm volatile("s_waitcnt vmcnt(1)" ::: "memory");
    }
    LDAF(A0c);
    if (pf) stageB(B1n, 1, k1);
    __builtin_amdgcn_s_barrier();
    MFMAQ(0, 1);
    __builtin_amdgcn_s_barrier();
  }
#undef LDAF
#undef LDBF
#undef MFMAQ
}

// ------------- stage 1: projection + tanh -> bf16, fused kxT write ----------
// grid (4 n, 32 m, 2 tensors): n on x so each XCD serves 1 B panel (L2-hot).
// For z==0 the epilogue also writes the transposed copy kxT[hb][d][s]
// (each thread's 4 consecutive-m values for fixed d pack into one 8B store).
__global__ __launch_bounds__(512, 2) void gemm_tanh_kernel(
    const u16* __restrict__ Ak, const u16* __restrict__ Aq,
    const u16* __restrict__ wTk, const u16* __restrict__ wTq,
    u16* __restrict__ kxo, u16* __restrict__ qxo, u16* __restrict__ kxT) {
  __shared__ alignas(16) u16 lds[2 * (2 * 128 * 64 + 2 * 128 * 64)];  // 128 KB
  const u16* A; const u16* W; u16* C;
  if (blockIdx.z == 0) { A = Ak; W = wTk; C = kxo; }
  else { A = Aq; W = wTq; C = qxo; }
  const bool isK = (blockIdx.z == 0);
  int nBase = blockIdx.x * 256;
  int mBase = blockIdx.y * 256;
  f32x4 acc[8][4];
#pragma unroll
  for (int i = 0; i < 8; ++i)
#pragma unroll
    for (int j = 0; j < 4; ++j) acc[i][j] = (f32x4){0.f, 0.f, 0.f, 0.f};
  gemm8_core<256>(A + (size_t)mBase * 1024, W + (size_t)nBase * 1024, 1024,
                  lds, acc);
  const int lane = threadIdx.x & 63, wid = threadIdx.x >> 6;
  const int wr = wid >> 2, wc = wid & 3, l15 = lane & 15, g = lane >> 4;
#pragma unroll
  for (int mf = 0; mf < 8; ++mf)
#pragma unroll
    for (int nf = 0; nf < 4; ++nf) {
      int m0 = mBase + wr * 128 + mf * 16 + g * 4;
      int n = nBase + wc * 64 + nf * 16 + l15;
      int h = n >> 7, d = n & 127;
      u16 t4[4];
#pragma unroll
      for (int j = 0; j < 4; ++j) {
        t4[j] = f2bf(fast_tanh(acc[mf][nf][j]));
        C[(size_t)h * 8192 * 128 + (size_t)(m0 + j) * 128 + d] = t4[j];
      }
      if (isK) {
        int b = m0 >> 10, s0 = m0 & 1023;
        *(uint2*)(kxT + (size_t)(h * 8 + b) * 131072 + (size_t)d * 1024 + s0) =
            *(uint2*)t4;
      }
    }
}

// ---------------------------- flash attention -------------------------------
// grid (64 hb, 4 qt); 512 thr = 8 waves x 32 q-rows = 256 q-rows/block.
// K/V staged once per block serve 2x the q-rows of the old 256-thr version
// (halves total staged traffic). Swapped QK^T, no-max softmax, dbuf staging.
__global__ __launch_bounds__(512, 2) void attn_kernel(const u16* __restrict__ qx,
                                                      const u16* __restrict__ kx,
                                                      const u16* __restrict__ kxT,
                                                      u16* __restrict__ X) {
  __shared__ alignas(16) u16 Klds[2][64 * 128];   // 32 KB
  __shared__ alignas(16) u16 Vlds[2][128 * 64];   // 32 KB
  __shared__ alignas(16) u16 Plds[8][32 * 64];    // 32 KB
  const int tid = threadIdx.x, lane = tid & 63, wid = tid >> 6;
  const int g = lane >> 4;
  const int hb = blockIdx.x, qt = blockIdx.y, h = hb >> 3, b = hb & 7;
  const u16* qxh = qx + ((size_t)h * 8192 + (size_t)b * 1024) * 128;
  const u16* kxh = kx + ((size_t)h * 8192 + (size_t)b * 1024) * 128;
  const u16* kxTh = kxT + (size_t)hb * 128 * 1024;
  const int q0 = qt * 256 + wid * 32;
  const float SC = 0.08838834764831845f * 1.44269504088896340f;

#define STAGE(buf, kt_)                                                        \
  do {                                                                         \
    _Pragma("unroll") for (int i_ = 0; i_ < 2; ++i_) {                         \
      int cIdx = (wid * 2 + i_) * 64 + lane;                                   \
      {                                                                        \
        int row = cIdx >> 4, slot = cIdx & 15;                                 \
        int src = slot ^ (row & 7);                                            \
        gload16((const char*)kxh + (size_t)((kt_) * 64 + row) * 256 + src * 16,\
                (char*)&Klds[buf][0] + (wid * 2 + i_) * 1024);                 \
      }                                                                        \
      {                                                                        \
        int row = cIdx >> 3, slot = cIdx & 7;                                  \
        int src = slot ^ (row & 7);                                            \
        gload16((const char*)kxTh + (size_t)row * 2048 + (kt_) * 128 + src * 16,\
                (char*)&Vlds[buf][0] + (wid * 2 + i_) * 1024);                 \
      }                                                                        \
    }                                                                          \
  } while (0)

  bf16x8 qa[2][4];
#pragma unroll
  for (int m = 0; m < 2; ++m)
#pragma unroll
    for (int kc = 0; kc < 4; ++kc)
      qa[m][kc] = *(const bf16x8*)(qxh + (size_t)(q0 + m * 16 + (lane & 15)) * 128
                                   + kc * 32 + g * 8);

  f32x4 os[2][8];
#pragma unroll
  for (int i = 0; i < 2; ++i)
#pragma unroll
    for (int j = 0; j < 8; ++j) os[i][j] = (f32x4){0.f, 0.f, 0.f, 0.f};
  float lsum[2] = {0.f, 0.f};

  u16* Pw = &Plds[wid][0];

  STAGE(0, 0);

  for (int kt = 0; kt < 16; ++kt) {
    const int cur = kt & 1;
    if (kt < 15) {
      STAGE(cur ^ 1, kt + 1);                       // 4 loads/thread
      asm volatile("s_waitcnt vmcnt(4)" ::: "memory");  // tile kt drained
    } else {
      asm volatile("s_waitcnt vmcnt(0)" ::: "memory");
    }
    __builtin_amdgcn_s_barrier();

    const u16* Kc = &Klds[cur][0];
    const u16* Vc = &Vlds[cur][0];

    f32x4 sa[4][2];
#pragma unroll
    for (int i = 0; i < 4; ++i)
#pragma unroll
      for (int j = 0; j < 2; ++j) sa[i][j] = (f32x4){0.f, 0.f, 0.f, 0.f};
    __builtin_amdgcn_s_setprio(1);
#pragma unroll
    for (int kc = 0; kc < 4; ++kc) {
      bf16x8 kb[4];
#pragma unroll
      for (int t = 0; t < 4; ++t) {
        int row = t * 16 + (lane & 15);
        int ch = kc * 4 + g;
        kb[t] = *(const bf16x8*)(Kc + row * 128 + ((ch ^ (row & 7)) << 3));
      }
#pragma unroll
      for (int t = 0; t < 4; ++t)
#pragma unroll
        for (int m = 0; m < 2; ++m)
          sa[t][m] = MFMA16(kb[t], qa[m][kc], sa[t][m]);
    }
    __builtin_amdgcn_s_setprio(0);

#pragma unroll
    for (int m = 0; m < 2; ++m) {
      int q = m * 16 + (lane & 15);
      int rowb = q * 128, q7 = q & 7;
#pragma unroll
      for (int t = 0; t < 4; ++t) {
        float p0 = EXP2(sa[t][m][0] * SC);
        float p1 = EXP2(sa[t][m][1] * SC);
        float p2 = EXP2(sa[t][m][2] * SC);
        float p3 = EXP2(sa[t][m][3] * SC);
        lsum[m] += (p0 + p1) + (p2 + p3);
        uint2 pk;
        pk.x = (u32)f2bf(p0) | ((u32)f2bf(p1) << 16);
        pk.y = (u32)f2bf(p2) | ((u32)f2bf(p3) << 16);
        int slot = (2 * t + (g >> 1)) ^ q7;
        *(uint2*)((char*)Pw + rowb + slot * 16 + 8 * (g & 1)) = pk;
      }
    }

    __builtin_amdgcn_s_setprio(1);
#pragma unroll
    for (int kc2 = 0; kc2 < 2; ++kc2) {
      bf16x8 pa[2], vb[8];
#pragma unroll
      for (int m = 0; m < 2; ++m) {
        int q = m * 16 + (lane & 15);
        int slot = (g + 4 * kc2) ^ (q & 7);
        pa[m] = *(const bf16x8*)((char*)Pw + q * 128 + slot * 16);
      }
#pragma unroll
      for (int nd = 0; nd < 8; ++nd) {
        int row = nd * 16 + (lane & 15);
        int ch = kc2 * 4 + g;
        vb[nd] = *(const bf16x8*)(Vc + row * 64 + ((ch ^ (row & 7)) << 3));
      }
#pragma unroll
      for (int m = 0; m < 2; ++m)
#pragma unroll
        for (int nd = 0; nd < 8; ++nd)
          os[m][nd] = MFMA16(pa[m], vb[nd], os[m][nd]);
    }
    __builtin_amdgcn_s_setprio(0);
    __builtin_amdgcn_s_barrier();
  }
#undef STAGE

#pragma unroll
  for (int m = 0; m < 2; ++m) {
    float s = lsum[m];
    s += __shfl_xor(s, 16);
    s += __shfl_xor(s, 32);
    lsum[m] = s;
  }

#pragma unroll
  for (int m = 0; m < 2; ++m)
#pragma unroll
    for (int j = 0; j < 4; ++j) {
      float tot = __shfl(lsum[m], 4 * g + j, 64);
      float inv = 1.f / tot;
      int qrow = b * 1024 + q0 + m * 16 + g * 4 + j;
#pragma unroll
      for (int nd = 0; nd < 8; ++nd) {
        int col = h * 128 + nd * 16 + (lane & 15);
        X[(size_t)qrow * 1024 + col] = f2bf(os[m][nd][j] * inv);
      }
    }
}

// ------------- stage 3: X @ proj_w^T + bias -> f32 out ----------------------
// grid (4 n, 64 m): n on x so each XCD serves 1 pwb panel (512 KB, L2-hot).
__global__ __launch_bounds__(512, 2) void gemm_bias_kernel(
    const u16* __restrict__ X, const u16* __restrict__ pw,
    const float* __restrict__ pb, float* __restrict__ out) {
  __shared__ alignas(16) u16 lds[2 * (2 * 64 * 64 + 2 * 128 * 64)];  // 96 KB
  int nBase = blockIdx.x * 256;
  int mBase = blockIdx.y * 128;
  f32x4 acc[4][4];
#pragma unroll
  for (int i = 0; i < 4; ++i)
#pragma unroll
    for (int j = 0; j < 4; ++j) acc[i][j] = (f32x4){0.f, 0.f, 0.f, 0.f};
  gemm8_core<128>(X + (size_t)mBase * 1024, pw + (size_t)nBase * 1024, 1024,
                  lds, acc);
  const int lane = threadIdx.x & 63, wid = threadIdx.x >> 6;
  const int wr = wid >> 2, wc = wid & 3, l15 = lane & 15, g = lane >> 4;
#pragma unroll
  for (int nf = 0; nf < 4; ++nf) {
    int e = nBase + wc * 64 + nf * 16 + l15;
    float bv = pb[e];
#pragma unroll
    for (int mf = 0; mf < 4; ++mf)
#pragma unroll
      for (int j = 0; j < 4; ++j) {
        int m = mBase + wr * 64 + mf * 16 + g * 4 + j;
        out[(size_t)m * 1024 + e] = acc[mf][nf][j] + bv;
      }
  }
}

extern "C" void kernel_launch(void* const* d_in, const int* in_sizes, int n_in,
                              void* d_out, int out_size, void* d_ws, size_t ws_size,
                              hipStream_t stream) {
  const float* k = (const float*)d_in[0];
  const float* q = (const float*)d_in[1];
  const float* wk = (const float*)d_in[3];
  const float* wq = (const float*)d_in[4];
  const float* pw = (const float*)d_in[5];
  const float* pb = (const float*)d_in[6];
  float* out = (float*)d_out;
  char* ws = (char*)d_ws;

  u16* kbf = (u16*)(ws);                       // 16 MB (reused as X later)
  u16* qbf = (u16*)(ws + (16ull << 20));       // 16 MB
  u16* wTk = (u16*)(ws + (32ull << 20));       // 2 MB
  u16* wTq = (u16*)(ws + (34ull << 20));       // 2 MB
  u16* pwb = (u16*)(ws + (36ull << 20));       // 2 MB
  u16* kx  = (u16*)(ws + (38ull << 20));       // 16 MB
  u16* qx  = (u16*)(ws + (54ull << 20));       // 16 MB
  u16* kxT = (u16*)(ws + (70ull << 20));       // 16 MB
  u16* X   = kbf;                              // alias: k_bf16 dead by then

  cvt_kernel<<<2048, 256, 0, stream>>>(k, kbf, 1048576);
  cvt_kernel<<<2048, 256, 0, stream>>>(q, qbf, 1048576);
  cvt_kernel<<<512, 256, 0, stream>>>(pw, pwb, 131072);
  wtrans_kernel<<<dim3(16, 2, 8), 256, 0, stream>>>(wk, wTk);
  wtrans_kernel<<<dim3(16, 2, 8), 256, 0, stream>>>(wq, wTq);
  gemm_tanh_kernel<<<dim3(4, 32, 2), 512, 0, stream>>>(kbf, qbf, wTk, wTq,
                                                       kx, qx, kxT);
  attn_kernel<<<dim3(64, 4), 512, 0, stream>>>(qx, kx, kxT, X);
  gemm_bias_kernel<<<dim3(4, 64), 512, 0, stream>>>(X, pwb, pb, out);
}

// Round 11
// 136.759 us; speedup vs baseline: 1.0359x; 1.0359x over previous
//
#include <hip/hip_runtime.h>

typedef unsigned short u16;
typedef unsigned int u32;
typedef __bf16 bf16x8 __attribute__((ext_vector_type(8)));
typedef float f32x4 __attribute__((ext_vector_type(4)));

#define MFMA16(a, b, c) __builtin_amdgcn_mfma_f32_16x16x32_bf16(a, b, c, 0, 0, 0)
#define EXP2(x) __builtin_amdgcn_exp2f(x)

typedef const void __attribute__((address_space(1)))* gas1_t;
typedef void __attribute__((address_space(3)))* las3_t;

__device__ __forceinline__ void gload16(const void* g, void* l) {
  __builtin_amdgcn_global_load_lds((gas1_t)g, (las3_t)l, 16, 0, 0);
}

__device__ __forceinline__ u16 f2bf(float f) {
  union { float f; u32 u; } v; v.f = f;
  u32 r = v.u + 0x7FFFu + ((v.u >> 16) & 1u);
  return (u16)(r >> 16);
}

// fast tanh via native exp2: tanh(x) = (e^2x - 1)/(e^2x + 1); bf16-accurate
__device__ __forceinline__ float fast_tanh(float x) {
  float xc = fminf(fmaxf(x, -20.f), 20.f);
  float t = EXP2(xc * 2.885390081777927f);  // 2*log2(e)
  return (t - 1.0f) * __builtin_amdgcn_rcpf(t + 1.0f);
}

// ---------------- elementwise f32 -> bf16 convert (8 elems/thread) ----------
__global__ __launch_bounds__(256) void cvt_kernel(const float* __restrict__ in,
                                                  u16* __restrict__ out, int n8) {
  int i = blockIdx.x * blockDim.x + threadIdx.x;
  int stride = gridDim.x * blockDim.x;
  for (; i < n8; i += stride) {
    const float4* p = (const float4*)(in + (size_t)i * 8);
    float4 a = p[0], b = p[1];
    u16 t[8];
    t[0] = f2bf(a.x); t[1] = f2bf(a.y); t[2] = f2bf(a.z); t[3] = f2bf(a.w);
    t[4] = f2bf(b.x); t[5] = f2bf(b.y); t[6] = f2bf(b.z); t[7] = f2bf(b.w);
    *(uint4*)(out + (size_t)i * 8) = *(uint4*)t;
  }
}

// ------------- w [H][E=1024][D=128] f32 -> wT [H][D][E] bf16 ----------------
__global__ __launch_bounds__(256) void wtrans_kernel(const float* __restrict__ w,
                                                     u16* __restrict__ wT) {
  __shared__ float t[64][65];
  int h = blockIdx.z;
  int e0 = blockIdx.x * 64, d0 = blockIdx.y * 64;
  const float* src = w + (size_t)h * 1024 * 128;
  u16* dst = wT + (size_t)h * 128 * 1024;
  int tid = threadIdx.x;
  {
    int row = tid >> 2, c0 = (tid & 3) * 16;
#pragma unroll
    for (int i = 0; i < 4; ++i) {
      float4 v = *(const float4*)(src + (size_t)(e0 + row) * 128 + d0 + c0 + i * 4);
      t[row][c0 + i * 4 + 0] = v.x;
      t[row][c0 + i * 4 + 1] = v.y;
      t[row][c0 + i * 4 + 2] = v.z;
      t[row][c0 + i * 4 + 3] = v.w;
    }
  }
  __syncthreads();
  {
    int dl = tid >> 2, c0 = (tid & 3) * 16;
    u16 tmp[16];
#pragma unroll
    for (int i = 0; i < 16; ++i) tmp[i] = f2bf(t[c0 + i][dl]);
    u16* o = dst + (size_t)(d0 + dl) * 1024 + e0 + c0;
    *(uint4*)o = *(uint4*)tmp;
    *(uint4*)(o + 8) = *(uint4*)(tmp + 8);
  }
}

// ======== 8-phase GEMM core (round-9, unchanged), BN=256 ====================
template <int BM>
__device__ __forceinline__ void gemm8_core(const u16* __restrict__ Ab,
                                           const u16* __restrict__ Bb,
                                           int K, u16* lds,
                                           f32x4 (&acc)[BM / 32][4]) {
  constexpr int MH = BM / 64;
  constexpr int HR = BM / 4;
  constexpr int AH = (BM / 2) * 64;
  constexpr int BH = 128 * 64;
  constexpr int BUF = 2 * AH + 2 * BH;
  constexpr int LA = BM / 128;
  const int tid = threadIdx.x, lane = tid & 63, wid = tid >> 6;
  const int wr = wid >> 2, wc = wid & 3, l15 = lane & 15, g = lane >> 4;
  const int nkt = K >> 6;
  const int arow = wr * HR;
  const int brow = wc * 32;

  auto stageA = [&](u16* dstHalf, int mh, int kt) {
#pragma unroll
    for (int i = 0; i < LA; ++i) {
      int c = (wid * LA + i) * 64 + lane;
      int rr = c >> 3, src = (c & 7) ^ (rr & 7);
      int grow = (rr / HR) * (2 * HR) + mh * HR + (rr % HR);
      gload16((const char*)Ab + ((size_t)grow * K + kt * 64 + src * 8) * 2,
              (char*)dstHalf + (wid * LA + i) * 1024);
    }
  };
  auto stageB = [&](u16* dstHalf, int nh, int kt) {
#pragma unroll
    for (int i = 0; i < 2; ++i) {
      int c = (wid * 2 + i) * 64 + lane;
      int cc = c >> 3, src = (c & 7) ^ (cc & 7);
      int gcol = (cc >> 5) * 64 + nh * 32 + (cc & 31);
      gload16((const char*)Bb + ((size_t)gcol * K + kt * 64 + src * 8) * 2,
              (char*)dstHalf + (wid * 2 + i) * 1024);
    }
  };

#define LDAF(half)                                                              \
  _Pragma("unroll") for (int m = 0; m < MH; ++m)                                \
  _Pragma("unroll") for (int kc = 0; kc < 2; ++kc) {                            \
    int r_ = arow + m * 16 + l15;                                               \
    af[m][kc] = *(const bf16x8*)((half) + r_ * 64 + (((kc * 4 + g) ^ (r_ & 7)) << 3)); \
  }
#define LDBF(half)                                                              \
  _Pragma("unroll") for (int n = 0; n < 2; ++n)                                 \
  _Pragma("unroll") for (int kc = 0; kc < 2; ++kc) {                            \
    int r_ = brow + n * 16 + l15;                                               \
    bb[n][kc] = *(const bf16x8*)((half) + r_ * 64 + (((kc * 4 + g) ^ (r_ & 7)) << 3)); \
  }
#define MFMAQ(MB, NB)                                                           \
  __builtin_amdgcn_s_setprio(1);                                                \
  _Pragma("unroll") for (int m = 0; m < MH; ++m)                                \
  _Pragma("unroll") for (int n = 0; n < 2; ++n)                                 \
  _Pragma("unroll") for (int kc = 0; kc < 2; ++kc)                              \
    acc[(MB) * MH + m][(NB) * 2 + n] =                                          \
        MFMA16(af[m][kc], bb[n][kc], acc[(MB) * MH + m][(NB) * 2 + n]);         \
  __builtin_amdgcn_s_setprio(0);

  stageA(lds, 0, 0);
  stageB(lds + 2 * AH, 0, 0);
  stageA(lds + AH, 1, 0);
  stageB(lds + 2 * AH + BH, 1, 0);
  if constexpr (BM == 256) asm volatile("s_waitcnt vmcnt(4)" ::: "memory");
  else                     asm volatile("s_waitcnt vmcnt(3)" ::: "memory");
  __builtin_amdgcn_s_barrier();

  bf16x8 af[MH][2], bb[2][2];
  for (int t = 0; t < nkt; ++t) {
    const int cur = t & 1;
    u16* A0c = lds + cur * BUF;
    u16* A1c = A0c + AH;
    u16* B0c = A0c + 2 * AH;
    u16* B1c = B0c + BH;
    u16* A0n = lds + (cur ^ 1) * BUF;
    u16* A1n = A0n + AH;
    u16* B0n = A0n + 2 * AH;
    u16* B1n = B0n + BH;
    const bool pf = (t + 1 < nkt);
    const int k1 = t + 1;

    asm volatile("s_waitcnt vmcnt(2)" ::: "memory");
    LDAF(A0c);
    LDBF(B0c);
    if (pf) stageA(A0n, 0, k1);
    __builtin_amdgcn_s_barrier();
    MFMAQ(0, 0);
    __builtin_amdgcn_s_barrier();

    if (pf) {
      if constexpr (BM == 256) asm volatile("s_waitcnt vmcnt(2)" ::: "memory");
      else                     asm volatile("s_waitcnt vmcnt(1)" ::: "memory");
    } else {
      asm volatile("s_waitcnt vmcnt(0)" ::: "memory");
    }
    LDAF(A1c);
    if (pf) stageB(B0n, 0, k1);
    __builtin_amdgcn_s_barrier();
    MFMAQ(1, 0);
    __builtin_amdgcn_s_barrier();

    LDBF(B1c);
    if (pf) stageA(A1n, 1, k1);
    __builtin_amdgcn_s_barrier();
    MFMAQ(1, 1);
    __builtin_amdgcn_s_barrier();

    if (pf) {
      if constexpr (BM == 256) asm volatile("s_waitcnt vmcnt(2)" ::: "memory");
      else                     asm volatile("s_waitcnt vmcnt(1)" ::: "memory");
    }
    LDAF(A0c);
    if (pf) stageB(B1n, 1, k1);
    __builtin_amdgcn_s_barrier();
    MFMAQ(0, 1);
    __builtin_amdgcn_s_barrier();
  }
#undef LDAF
#undef LDBF
#undef MFMAQ
}

// ------------- stage 1: projection + tanh -> bf16, fused kxT write ----------
// grid (32 m, 4 n, 2 tensors): m on blockIdx.x so the 4 blocks sharing an
// A-row-panel land on the SAME XCD (id = m + 32*n -> XCD = m%8) — A (16 MB)
// is the operand whose L2 locality matters. For z==0 the epilogue also writes
// the transposed copy kxT[hb][d][s] (4 consecutive-m values -> one 8B store).
__global__ __launch_bounds__(512, 2) void gemm_tanh_kernel(
    const u16* __restrict__ Ak, const u16* __restrict__ Aq,
    const u16* __restrict__ wTk, const u16* __restrict__ wTq,
    u16* __restrict__ kxo, u16* __restrict__ qxo, u16* __restrict__ kxT) {
  __shared__ alignas(16) u16 lds[2 * (2 * 128 * 64 + 2 * 128 * 64)];  // 128 KB
  const u16* A; const u16* W; u16* C;
  if (blockIdx.z == 0) { A = Ak; W = wTk; C = kxo; }
  else { A = Aq; W = wTq; C = qxo; }
  const bool isK = (blockIdx.z == 0);
  int mBase = blockIdx.x * 256;
  int nBase = blockIdx.y * 256;
  f32x4 acc[8][4];
#pragma unroll
  for (int i = 0; i < 8; ++i)
#pragma unroll
    for (int j = 0; j < 4; ++j) acc[i][j] = (f32x4){0.f, 0.f, 0.f, 0.f};
  gemm8_core<256>(A + (size_t)mBase * 1024, W + (size_t)nBase * 1024, 1024,
                  lds, acc);
  const int lane = threadIdx.x & 63, wid = threadIdx.x >> 6;
  const int wr = wid >> 2, wc = wid & 3, l15 = lane & 15, g = lane >> 4;
#pragma unroll
  for (int mf = 0; mf < 8; ++mf)
#pragma unroll
    for (int nf = 0; nf < 4; ++nf) {
      int m0 = mBase + wr * 128 + mf * 16 + g * 4;
      int n = nBase + wc * 64 + nf * 16 + l15;
      int h = n >> 7, d = n & 127;
      u16 t4[4];
#pragma unroll
      for (int j = 0; j < 4; ++j) {
        t4[j] = f2bf(fast_tanh(acc[mf][nf][j]));
        C[(size_t)h * 8192 * 128 + (size_t)(m0 + j) * 128 + d] = t4[j];
      }
      if (isK) {
        int b = m0 >> 10, s0 = m0 & 1023;
        *(uint2*)(kxT + (size_t)(h * 8 + b) * 131072 + (size_t)d * 1024 + s0) =
            *(uint2*)t4;
      }
    }
}

// ---------------------------- flash attention -------------------------------
// grid (64 hb, 4 qt); 512 thr = 8 waves x 32 q-rows = 256 q-rows/block.
// K/V staged once per block serve 2x the q-rows (halved staged traffic).
// Swapped QK^T, no-max softmax, dbuf staging with counted vmcnt.
__global__ __launch_bounds__(512, 2) void attn_kernel(const u16* __restrict__ qx,
                                                      const u16* __restrict__ kx,
                                                      const u16* __restrict__ kxT,
                                                      u16* __restrict__ X) {
  __shared__ alignas(16) u16 Klds[2][64 * 128];   // 32 KB
  __shared__ alignas(16) u16 Vlds[2][128 * 64];   // 32 KB
  __shared__ alignas(16) u16 Plds[8][32 * 64];    // 32 KB
  const int tid = threadIdx.x, lane = tid & 63, wid = tid >> 6;
  const int g = lane >> 4;
  const int hb = blockIdx.x, qt = blockIdx.y, h = hb >> 3, b = hb & 7;
  const u16* qxh = qx + ((size_t)h * 8192 + (size_t)b * 1024) * 128;
  const u16* kxh = kx + ((size_t)h * 8192 + (size_t)b * 1024) * 128;
  const u16* kxTh = kxT + (size_t)hb * 128 * 1024;
  const int q0 = qt * 256 + wid * 32;
  const float SC = 0.08838834764831845f * 1.44269504088896340f;

#define STAGE(buf, kt_)                                                        \
  do {                                                                         \
    _Pragma("unroll") for (int i_ = 0; i_ < 2; ++i_) {                         \
      int cIdx = (wid * 2 + i_) * 64 + lane;                                   \
      {                                                                        \
        int row = cIdx >> 4, slot = cIdx & 15;                                 \
        int src = slot ^ (row & 7);                                            \
        gload16((const char*)kxh + (size_t)((kt_) * 64 + row) * 256 + src * 16,\
                (char*)&Klds[buf][0] + (wid * 2 + i_) * 1024);                 \
      }                                                                        \
      {                                                                        \
        int row = cIdx >> 3, slot = cIdx & 7;                                  \
        int src = slot ^ (row & 7);                                            \
        gload16((const char*)kxTh + (size_t)row * 2048 + (kt_) * 128 + src * 16,\
                (char*)&Vlds[buf][0] + (wid * 2 + i_) * 1024);                 \
      }                                                                        \
    }                                                                          \
  } while (0)

  bf16x8 qa[2][4];
#pragma unroll
  for (int m = 0; m < 2; ++m)
#pragma unroll
    for (int kc = 0; kc < 4; ++kc)
      qa[m][kc] = *(const bf16x8*)(qxh + (size_t)(q0 + m * 16 + (lane & 15)) * 128
                                   + kc * 32 + g * 8);

  f32x4 os[2][8];
#pragma unroll
  for (int i = 0; i < 2; ++i)
#pragma unroll
    for (int j = 0; j < 8; ++j) os[i][j] = (f32x4){0.f, 0.f, 0.f, 0.f};
  float lsum[2] = {0.f, 0.f};

  u16* Pw = &Plds[wid][0];

  STAGE(0, 0);

  for (int kt = 0; kt < 16; ++kt) {
    const int cur = kt & 1;
    if (kt < 15) {
      STAGE(cur ^ 1, kt + 1);                       // 4 loads/thread
      asm volatile("s_waitcnt vmcnt(4)" ::: "memory");  // tile kt drained
    } else {
      asm volatile("s_waitcnt vmcnt(0)" ::: "memory");
    }
    __builtin_amdgcn_s_barrier();

    const u16* Kc = &Klds[cur][0];
    const u16* Vc = &Vlds[cur][0];

    f32x4 sa[4][2];
#pragma unroll
    for (int i = 0; i < 4; ++i)
#pragma unroll
      for (int j = 0; j < 2; ++j) sa[i][j] = (f32x4){0.f, 0.f, 0.f, 0.f};
    __builtin_amdgcn_s_setprio(1);
#pragma unroll
    for (int kc = 0; kc < 4; ++kc) {
      bf16x8 kb[4];
#pragma unroll
      for (int t = 0; t < 4; ++t) {
        int row = t * 16 + (lane & 15);
        int ch = kc * 4 + g;
        kb[t] = *(const bf16x8*)(Kc + row * 128 + ((ch ^ (row & 7)) << 3));
      }
#pragma unroll
      for (int t = 0; t < 4; ++t)
#pragma unroll
        for (int m = 0; m < 2; ++m)
          sa[t][m] = MFMA16(kb[t], qa[m][kc], sa[t][m]);
    }
    __builtin_amdgcn_s_setprio(0);

#pragma unroll
    for (int m = 0; m < 2; ++m) {
      int q = m * 16 + (lane & 15);
      int rowb = q * 128, q7 = q & 7;
#pragma unroll
      for (int t = 0; t < 4; ++t) {
        float p0 = EXP2(sa[t][m][0] * SC);
        float p1 = EXP2(sa[t][m][1] * SC);
        float p2 = EXP2(sa[t][m][2] * SC);
        float p3 = EXP2(sa[t][m][3] * SC);
        lsum[m] += (p0 + p1) + (p2 + p3);
        uint2 pk;
        pk.x = (u32)f2bf(p0) | ((u32)f2bf(p1) << 16);
        pk.y = (u32)f2bf(p2) | ((u32)f2bf(p3) << 16);
        int slot = (2 * t + (g >> 1)) ^ q7;
        *(uint2*)((char*)Pw + rowb + slot * 16 + 8 * (g & 1)) = pk;
      }
    }

    __builtin_amdgcn_s_setprio(1);
#pragma unroll
    for (int kc2 = 0; kc2 < 2; ++kc2) {
      bf16x8 pa[2], vb[8];
#pragma unroll
      for (int m = 0; m < 2; ++m) {
        int q = m * 16 + (lane & 15);
        int slot = (g + 4 * kc2) ^ (q & 7);
        pa[m] = *(const bf16x8*)((char*)Pw + q * 128 + slot * 16);
      }
#pragma unroll
      for (int nd = 0; nd < 8; ++nd) {
        int row = nd * 16 + (lane & 15);
        int ch = kc2 * 4 + g;
        vb[nd] = *(const bf16x8*)(Vc + row * 64 + ((ch ^ (row & 7)) << 3));
      }
#pragma unroll
      for (int m = 0; m < 2; ++m)
#pragma unroll
        for (int nd = 0; nd < 8; ++nd)
          os[m][nd] = MFMA16(pa[m], vb[nd], os[m][nd]);
    }
    __builtin_amdgcn_s_setprio(0);
    __builtin_amdgcn_s_barrier();
  }
#undef STAGE

#pragma unroll
  for (int m = 0; m < 2; ++m) {
    float s = lsum[m];
    s += __shfl_xor(s, 16);
    s += __shfl_xor(s, 32);
    lsum[m] = s;
  }

#pragma unroll
  for (int m = 0; m < 2; ++m)
#pragma unroll
    for (int j = 0; j < 4; ++j) {
      float tot = __shfl(lsum[m], 4 * g + j, 64);
      float inv = 1.f / tot;
      int qrow = b * 1024 + q0 + m * 16 + g * 4 + j;
#pragma unroll
      for (int nd = 0; nd < 8; ++nd) {
        int col = h * 128 + nd * 16 + (lane & 15);
        X[(size_t)qrow * 1024 + col] = f2bf(os[m][nd][j] * inv);
      }
    }
}

// ------------- stage 3: X @ proj_w^T + bias -> f32 out ----------------------
// grid (64 m, 4 n): m on x -> same-A blocks share an XCD (X is 16 MB).
__global__ __launch_bounds__(512, 2) void gemm_bias_kernel(
    const u16* __restrict__ X, const u16* __restrict__ pw,
    const float* __restrict__ pb, float* __restrict__ out) {
  __shared__ alignas(16) u16 lds[2 * (2 * 64 * 64 + 2 * 128 * 64)];  // 96 KB
  int mBase = blockIdx.x * 128;
  int nBase = blockIdx.y * 256;
  f32x4 acc[4][4];
#pragma unroll
  for (int i = 0; i < 4; ++i)
#pragma unroll
    for (int j = 0; j < 4; ++j) acc[i][j] = (f32x4){0.f, 0.f, 0.f, 0.f};
  gemm8_core<128>(X + (size_t)mBase * 1024, pw + (size_t)nBase * 1024, 1024,
                  lds, acc);
  const int lane = threadIdx.x & 63, wid = threadIdx.x >> 6;
  const int wr = wid >> 2, wc = wid & 3, l15 = lane & 15, g = lane >> 4;
#pragma unroll
  for (int nf = 0; nf < 4; ++nf) {
    int e = nBase + wc * 64 + nf * 16 + l15;
    float bv = pb[e];
#pragma unroll
    for (int mf = 0; mf < 4; ++mf)
#pragma unroll
      for (int j = 0; j < 4; ++j) {
        int m = mBase + wr * 64 + mf * 16 + g * 4 + j;
        out[(size_t)m * 1024 + e] = acc[mf][nf][j] + bv;
      }
  }
}

extern "C" void kernel_launch(void* const* d_in, const int* in_sizes, int n_in,
                              void* d_out, int out_size, void* d_ws, size_t ws_size,
                              hipStream_t stream) {
  const float* k = (const float*)d_in[0];
  const float* q = (const float*)d_in[1];
  const float* wk = (const float*)d_in[3];
  const float* wq = (const float*)d_in[4];
  const float* pw = (const float*)d_in[5];
  const float* pb = (const float*)d_in[6];
  float* out = (float*)d_out;
  char* ws = (char*)d_ws;

  u16* kbf = (u16*)(ws);                       // 16 MB (reused as X later)
  u16* qbf = (u16*)(ws + (16ull << 20));       // 16 MB
  u16* wTk = (u16*)(ws + (32ull << 20));       // 2 MB
  u16* wTq = (u16*)(ws + (34ull << 20));       // 2 MB
  u16* pwb = (u16*)(ws + (36ull << 20));       // 2 MB
  u16* kx  = (u16*)(ws + (38ull << 20));       // 16 MB
  u16* qx  = (u16*)(ws + (54ull << 20));       // 16 MB
  u16* kxT = (u16*)(ws + (70ull << 20));       // 16 MB
  u16* X   = kbf;                              // alias: k_bf16 dead by then

  cvt_kernel<<<2048, 256, 0, stream>>>(k, kbf, 1048576);
  cvt_kernel<<<2048, 256, 0, stream>>>(q, qbf, 1048576);
  cvt_kernel<<<512, 256, 0, stream>>>(pw, pwb, 131072);
  wtrans_kernel<<<dim3(16, 2, 8), 256, 0, stream>>>(wk, wTk);
  wtrans_kernel<<<dim3(16, 2, 8), 256, 0, stream>>>(wq, wTq);
  gemm_tanh_kernel<<<dim3(32, 4, 2), 512, 0, stream>>>(kbf, qbf, wTk, wTq,
                                                       kx, qx, kxT);
  attn_kernel<<<dim3(64, 4), 512, 0, stream>>>(qx, kx, kxT, X);
  gemm_bias_kernel<<<dim3(64, 4), 512, 0, stream>>>(X, pwb, pb, out);
}